// Round 9
// baseline (25308.321 us; speedup 1.0000x reference)
//
#include <hip/hip_runtime.h>
#include <hip/hip_bf16.h>

typedef __attribute__((ext_vector_type(8))) short bf16x8;
typedef __attribute__((ext_vector_type(4))) float f32x4;
typedef __attribute__((ext_vector_type(4))) float fvec4;
typedef __attribute__((ext_vector_type(4))) unsigned short u16x4;
typedef __attribute__((ext_vector_type(4))) int i32x4;

#define DEVI __device__ __forceinline__

constexpr int BB = 256, TT = 1024, FF = 128, HH = 512, OO = 64;
constexpr int KK = 256;    // fused input width [x_imp | m]
constexpr int NN = 2048;   // fused gate width  [z | r | htilde | gamma_h]

DEVI unsigned short f2bf(float x) {
  unsigned int u = __float_as_uint(x);
  u += 0x7FFFu + ((u >> 16) & 1u);          // RNE
  return (unsigned short)(u >> 16);
}
DEVI float bf2f(unsigned short s) {
  return __uint_as_float(((unsigned int)s) << 16);
}

DEVI void gload16(const void* g, void* lds) {
  __builtin_amdgcn_global_load_lds(
      (const __attribute__((address_space(1))) void*)g,
      (__attribute__((address_space(3))) void*)lds, 16, 0, 0);
}

DEVI void barrier_lds() {       // raw barrier: waits LDS ops only, vmcnt SURVIVES
  asm volatile("s_waitcnt lgkmcnt(0)" ::: "memory");
  __builtin_amdgcn_s_barrier();
  __builtin_amdgcn_sched_barrier(0);
}

// opacity: forbid rematerialization/sinking of a pinned register value
DEVI void pin_opaque(i32x4& v) {
  asm volatile("" : "+v"(v));
}

// slabHG address swizzle (shorts): involution within a row, applied on BOTH
// the stage source and every read/write.
DEVI int hgIdx(int row, int c) { return row*1024 + (c ^ ((row & 7) << 3)); }

// ---------------------------------------------------------------------------
// K0a: per-column scales s_n = max_k |U[k][n]|  (z:0..511, r:512..1023, h:1024..1535)
// ---------------------------------------------------------------------------
__global__ __launch_bounds__(256) void prep_scales_kernel(
    const float* __restrict__ U_z, const float* __restrict__ U_r,
    const float* __restrict__ Uh, float* __restrict__ uscale)
{
  int n = blockIdx.x * 256 + threadIdx.x;
  if (n >= 1536) return;
  const float* src = (n < 512) ? U_z : (n < 1024) ? U_r : Uh;
  int col = n & 511;
  float s = 0.f;
  for (int k = 0; k < HH; ++k) s = fmaxf(s, fabsf(src[k*HH + col]));
  uscale[n] = fmaxf(s, 1e-30f);
}

// ---------------------------------------------------------------------------
// K0b: pack weights.
//   BwT [2048][256] bf16 : row n = column n of fused K x N weight.
//   bias[2048] f32 : b_* + colsum(V_*)  (gamma rows: b_gamma_h)
//   UzrQ i8 [8 kt][64 nt][64 l][16 j] : nt<32 -> U_z cols, else U_r cols
//   UhQ  i8 [8 kt][32 nt][64 l][16 j] : U
//   value (kt,nt,l,j) = round(U[k][col]/s_col*127), k = kt*64+(l>>4)*16+j,
//   col = (nt&31)*16+(l&15).  A-side uses the identical (p=l>>4, j)->k map.
// ---------------------------------------------------------------------------
__global__ __launch_bounds__(256) void prep_kernel(
    const float* __restrict__ W_z, const float* __restrict__ V_z, const float* __restrict__ b_z,
    const float* __restrict__ W_r, const float* __restrict__ V_r, const float* __restrict__ b_r,
    const float* __restrict__ Wh,  const float* __restrict__ Vh,  const float* __restrict__ bh,
    const float* __restrict__ Wgh, const float* __restrict__ bgh,
    const float* __restrict__ U_z, const float* __restrict__ U_r, const float* __restrict__ Uh,
    const float* __restrict__ uscale,
    unsigned short* __restrict__ BwT, float* __restrict__ bias,
    int* __restrict__ UzrQ, int* __restrict__ UhQ)
{
  int idx = blockIdx.x * 256 + threadIdx.x;
  if (idx < 524288) {                       // BwT
    int n = idx >> 8, k = idx & 255;
    float v;
    if (n < 512)       { int h = n;        v = (k < 128) ? W_z[k*HH + h] : -V_z[(k-128)*HH + h]; }
    else if (n < 1024) { int h = n - 512;  v = (k < 128) ? W_r[k*HH + h] : -V_r[(k-128)*HH + h]; }
    else if (n < 1536) { int h = n - 1024; v = (k < 128) ? Wh [k*HH + h] : -Vh [(k-128)*HH + h]; }
    else               { int h = n - 1536; v = (k < 128) ? 0.f : Wgh[(k-128)*HH + h]; }
    BwT[n*256 + k] = f2bf(v);
    return;
  }
  idx -= 524288;
  if (idx < 2048) {                         // bias
    int n = idx; float v;
    if (n < 512)       { float s = b_z[n];      for (int f = 0; f < FF; ++f) s += V_z[f*HH + n];        v = s; }
    else if (n < 1024) { int h = n-512;  float s = b_r[h]; for (int f = 0; f < FF; ++f) s += V_r[f*HH + h]; v = s; }
    else if (n < 1536) { int h = n-1024; float s = bh[h];  for (int f = 0; f < FF; ++f) s += Vh[f*HH + h];  v = s; }
    else               { v = bgh[n-1536]; }
    bias[n] = v;
    return;
  }
  idx -= 2048;
  if (idx < 131072) {                       // UzrQ words
    int j0 = (idx & 3) * 4;
    int l  = (idx >> 2) & 63;
    int nt = (idx >> 8) & 63;
    int kt = idx >> 14;
    int col = (nt & 31)*16 + (l & 15);
    const float* src = (nt < 32) ? U_z : U_r;
    float sc = 127.f / uscale[(nt < 32 ? 0 : 512) + col];
    int word = 0;
#pragma unroll
    for (int b = 0; b < 4; ++b) {
      int k = kt*64 + (l >> 4)*16 + j0 + b;
      float q = fminf(fmaxf(rintf(src[k*HH + col] * sc), -127.f), 127.f);
      word |= ((int)q & 0xFF) << (8*b);
    }
    UzrQ[idx] = word;
    return;
  }
  idx -= 131072;
  if (idx < 65536) {                        // UhQ words
    int j0 = (idx & 3) * 4;
    int l  = (idx >> 2) & 63;
    int nt = (idx >> 8) & 31;
    int kt = idx >> 13;
    int col = nt*16 + (l & 15);
    float sc = 127.f / uscale[1024 + col];
    int word = 0;
#pragma unroll
    for (int b = 0; b < 4; ++b) {
      int k = kt*64 + (l >> 4)*16 + j0 + b;
      float q = fminf(fmaxf(rintf(Uh[k*HH + col] * sc), -127.f), 127.f);
      word |= ((int)q & 0xFF) << (8*b);
    }
    UhQ[idx] = word;
  }
}

// ---------------------------------------------------------------------------
// K1: imputation + fused A chunk [B*TC][256] bf16 = [x_imp | m]
// ---------------------------------------------------------------------------
__global__ __launch_bounds__(256) void build_A_kernel(
    const float* __restrict__ x, const float* __restrict__ delta,
    const float* __restrict__ mm, const float* __restrict__ xf,
    const float* __restrict__ Wgx, const float* __restrict__ bgx,
    const int* __restrict__ bs, unsigned short* __restrict__ A,
    int t0, int TC)
{
  int blk = blockIdx.x;
  int row8 = blk * 8;
  int b0  = row8 / TC;
  int tl0 = row8 % TC;
  if (b0 >= bs[t0 + tl0]) return;
  int tid = threadIdx.x;
  int rl = row8 + (tid >> 5);
  int tc = tl0 + (tid >> 5);
  long gi = ((long)b0*TT + t0 + tc) * 32 + (tid & 31);
  int f0 = (tid & 31) * 4;
  fvec4 xv = ((const fvec4*)x)[gi];
  fvec4 dv = ((const fvec4*)delta)[gi];
  fvec4 mv = ((const fvec4*)mm)[gi];
  fvec4 fv = ((const fvec4*)xf)[gi];
  unsigned short ox[4], om[4];
#pragma unroll
  for (int j = 0; j < 4; ++j) {
    float g  = __expf(-fmaxf(dv[j]*Wgx[f0+j] + bgx[f0+j], 0.f));
    float xr = g*fv[j] + (1.f - g)*0.001f;
    float xi = (mv[j] > 0.5f) ? xr : xv[j];
    ox[j] = f2bf(xi); om[j] = f2bf(mv[j]);
  }
  *(u16x4*)(A + (long)rl*KK + f0)       = (u16x4){ox[0], ox[1], ox[2], ox[3]};
  *(u16x4*)(A + (long)rl*KK + 128 + f0) = (u16x4){om[0], om[1], om[2], om[3]};
}

// ---------------------------------------------------------------------------
// K2: chunk GEMM  PRE[m][n] = A[m][:] @ Bw[:,n] + bias[n]  (bf16 MFMA, K=256)
// ---------------------------------------------------------------------------
__global__ __launch_bounds__(256) void gemm1_kernel(
    const unsigned short* __restrict__ A, const unsigned short* __restrict__ BwT,
    const float* __restrict__ bias, const int* __restrict__ bs,
    unsigned short* __restrict__ PRE, int t0, int TC)
{
  int blk = blockIdx.x;
  int nt = blk & 15;
  int mt = blk >> 4;
  {
    int m0 = mt * 128;
    int b_ = m0 / TC;
    int bcheck = (TC >= 128) ? bs[t0 + (m0 % TC)] : bs[t0];
    if (b_ >= bcheck) return;
  }
  int tid = threadIdx.x;
  int w = tid >> 6, l = tid & 63;
  int wm = w >> 1, wn = w & 1;
  int lr = l & 15, lg = l >> 4;
  int m_base = mt*128 + wm*64;
  int n_base = nt*128 + wn*64;
  const unsigned short* Aptr = A   + (long)(m_base + lr)*KK + lg*8;
  const unsigned short* Bptr = BwT + (long)(n_base + lr)*KK + lg*8;
  f32x4 acc[4][4];
#pragma unroll
  for (int i = 0; i < 4; ++i)
#pragma unroll
    for (int j = 0; j < 4; ++j) acc[i][j] = (f32x4){0.f, 0.f, 0.f, 0.f};

#pragma unroll
  for (int kt = 0; kt < 8; ++kt) {
    bf16x8 af[4], bfr[4];
#pragma unroll
    for (int i = 0; i < 4; ++i) af[i]  = *(const bf16x8*)(Aptr + (long)i*16*KK + kt*32);
#pragma unroll
    for (int i = 0; i < 4; ++i) bfr[i] = *(const bf16x8*)(Bptr + (long)i*16*KK + kt*32);
#pragma unroll
    for (int ms = 0; ms < 4; ++ms)
#pragma unroll
      for (int ns = 0; ns < 4; ++ns)
        acc[ms][ns] = __builtin_amdgcn_mfma_f32_16x16x32_bf16(af[ms], bfr[ns], acc[ms][ns], 0, 0, 0);
  }
#pragma unroll
  for (int ms = 0; ms < 4; ++ms) {
    int gm0 = m_base + ms*16 + lg*4;
#pragma unroll
    for (int ns = 0; ns < 4; ++ns) {
      int gn = n_base + ns*16 + lr;
      float bv = bias[gn];
      bool is_gamma = (gn >= 1536);
#pragma unroll
      for (int q = 0; q < 4; ++q) {
        float v = acc[ms][ns][q] + bv;
        if (is_gamma) v = __expf(-fmaxf(v, 0.f));
        PRE[(long)(gm0 + q)*NN + gn] = f2bf(v);
      }
    }
  }
}

// ---------------------------------------------------------------------------
// K3: sequential scan, 16 blocks x 512 threads (8 waves), i8 MFMA (K=64).
//   6 of each wave's 24 U units (96 VGPRs) pinned in registers for the whole
//   chunk; asm-opacity prevents the allocator from sinking/rematerializing
//   the pin loads into the loop (the round-7/8 failure). waves_per_eu(2)
//   makes the 256-VGPR budget explicit (LDS caps us at 1 block/CU anyway).
//   Remaining 18 units streamed per step via depth-2 global_load_lds
//   pipeline with counted vmcnt.
// ---------------------------------------------------------------------------
__global__ __launch_bounds__(512, 2) __attribute__((amdgpu_waves_per_eu(2)))
void scan_kernel(
    const unsigned short* __restrict__ PRE,
    const signed char* __restrict__ UzrQ,
    const signed char* __restrict__ UhQ,
    const float* __restrict__ uscale,
    const int* __restrict__ bs,
    float* __restrict__ h_st,
    float* __restrict__ sbuf,
    int t0, int TC)
{
  __shared__ __align__(16) signed char Ubuf[8][2][4096];   // 64 KB per-wave dbuf
  __shared__ __align__(16) i32x4 hd_l[8*64];               // 8 KB hd / a2 frags
  __shared__ __align__(16) unsigned short slabHG[16*1024]; // 32 KB [row][htld|r : gamma]
  __shared__ float hm[16][524];                            // 33.5 KB h master
  __shared__ float wmax[8];

  const int tid = threadIdx.x;
  const int r0 = blockIdx.x * 16;
  if (t0 > 0 && bs[t0] <= r0) return;

  const int w = tid >> 6, l = tid & 63, lr = l & 15, lg = l >> 4;
  const size_t rowStr = (size_t)TC * NN;

  signed char* slot0 = &Ubuf[w][0][0];
  signed char* slot1 = &Ubuf[w][1][0];

  auto STAGEA = [&](int u) {   // phase-A unit: kt=u>>1, half=u&1 (0=z,1=r), tiles {4w..4w+3}
    const signed char* src = UzrQ + ((size_t)(((u>>1)*64 + (u&1)*32 + w*4)*64) + l)*16;
    signed char* dst = (u & 1) ? slot1 : slot0;
#pragma unroll
    for (int i = 0; i < 4; ++i) gload16(src + (size_t)i*1024, dst + i*1024);
  };
  auto STAGEB = [&](int u) {   // phase-B unit: kt=u, tiles {4w..4w+3}
    const signed char* src = UhQ + ((size_t)((u*32 + w*4)*64) + l)*16;
    signed char* dst = (u & 1) ? slot1 : slot0;
#pragma unroll
    for (int i = 0; i < 4; ++i) gload16(src + (size_t)i*1024, dst + i*1024);
  };
  auto STAGEHG = [&](const unsigned short* PREn) {  // htilde+gamma halves, swizzled source
#pragma unroll
    for (int j = 0; j < 4; ++j) {
      int idx = w*4 + j;
      int row = idx >> 1;
      int phys = (idx & 1)*512 + l*8;
      int logi = phys ^ ((row & 7) << 3);
      const unsigned short* src = PREn + (size_t)row*rowStr + 1024 + logi;
      gload16(src, &slabHG[idx*512]);
    }
  };

  // per-thread dequant constants
  float zdq[4], rdq[4], hdq[4];
#pragma unroll
  for (int i = 0; i < 4; ++i) {
    int c = (w*4 + i)*16 + lr;
    zdq[i] = uscale[c]        * (1.f/16129.f);
    rdq[i] = uscale[512 + c]  * (1.f/16129.f);
    hdq[i] = uscale[1024 + c] * (1.f/16129.f);
  }
  if (tid < 8) wmax[tid] = (t0 == 0) ? 1e-20f : sbuf[blockIdx.x];

  // ---- pinned U units (persist in VGPRs for the whole chunk) ----
  // phase-A units 0..3 (kt 0..1, z and r halves), phase-B units 0..1 (kt 0..1)
  i32x4 pinA[4][4], pinB[2][4];
#pragma unroll
  for (int u = 0; u < 4; ++u)
#pragma unroll
    for (int i = 0; i < 4; ++i)
      pinA[u][i] = ((const i32x4*)UzrQ)[((u>>1)*64 + (u&1)*32 + w*4 + i)*64 + l];
#pragma unroll
  for (int u = 0; u < 2; ++u)
#pragma unroll
    for (int i = 0; i < 4; ++i)
      pinB[u][i] = ((const i32x4*)UhQ)[(u*32 + w*4 + i)*64 + l];
  asm volatile("s_waitcnt vmcnt(0)" ::: "memory");  // pin loads landed
  // opacity: values can no longer be rematerialized -> must stay in VGPRs
#pragma unroll
  for (int u = 0; u < 4; ++u)
#pragma unroll
    for (int i = 0; i < 4; ++i) pin_opaque(pinA[u][i]);
#pragma unroll
  for (int u = 0; u < 2; ++u)
#pragma unroll
    for (int i = 0; i < 4; ++i) pin_opaque(pinB[u][i]);

  if (t0 == 0) {
    for (int i = tid; i < 16*512; i += 512) hm[i>>9][i&511] = 0.f;
  } else {
    for (int i = tid; i < 16*512; i += 512)
      hm[i>>9][i&511] = h_st[(size_t)(r0 + (i>>9))*HH + (i&511)];
  }
  asm volatile("s_waitcnt vmcnt(0)" ::: "memory");  // hm loads fully done
  __builtin_amdgcn_sched_barrier(0);

  // prologue staging: HG(step 0), A4, A5  (12 loads outstanding)
  STAGEHG(PRE + (size_t)r0*TC*NN);
  STAGEA(4); STAGEA(5);

  for (int tc = 0; tc < TC; ++tc) {
    const int bsv = bs[t0 + tc];
    if (bsv <= r0) break;                  // descending bs: done forever
    const int na = min(16, bsv - r0);
    const unsigned short* PREstep = PRE + ((size_t)r0*TC + tc)*NN;
    const unsigned short* PREnext = PREstep + NN;

    barrier_lds();                         // S1: prev hm + wmax writes visible
    asm volatile("s_waitcnt vmcnt(8)" ::: "memory");  // HG landed; A4,A5 fly
    __builtin_amdgcn_sched_barrier(0);

    // dynamic quant scale for hd (exact bound: |hd| <= max|h| = s)
    float s = wmax[0];
#pragma unroll
    for (int i = 1; i < 8; ++i) s = fmaxf(s, wmax[i]);
    const float qs = 127.f / s;

    // pz/pr clump: the only VGPR global loads in the loop
    unsigned short pzr[2][4][4];
#pragma unroll
    for (int i = 0; i < 4; ++i)
#pragma unroll
      for (int q = 0; q < 4; ++q) {
        int row = lg*4 + q, col = (w*4 + i)*16 + lr;
        const unsigned short* pb = PREstep + (size_t)row*rowStr + col;
        pzr[0][i][q] = pb[0];
        pzr[1][i][q] = pb[512];
      }
    __builtin_amdgcn_sched_barrier(0);

    // hd build (one pass: kt = w): quantize (act? gamma*h : h) to i8 frags
    {
      const int k0 = w*64 + lg*16;
      const bool act = lr < na;
      bf16x8 g0 = *(const bf16x8*)&slabHG[hgIdx(lr, 512 + k0)];
      bf16x8 g1 = *(const bf16x8*)&slabHG[hgIdx(lr, 512 + k0 + 8)];
      i32x4 qw;
#pragma unroll
      for (int d = 0; d < 4; ++d) {
        int word = 0;
#pragma unroll
        for (int b = 0; b < 4; ++b) {
          int j = d*4 + b;
          float h  = hm[lr][k0 + j];
          float gv = bf2f((unsigned short)(j < 8 ? g0[j] : g1[j-8]));
          float hd = act ? gv*h : h;
          float q  = fminf(fmaxf(rintf(hd*qs), -127.f), 127.f);
          word |= ((int)q & 0xFF) << (8*b);
        }
        qw[d] = word;
      }
      hd_l[w*64 + l] = qw;
    }

    // hoist htilde-preact + gamma for my output cells (before r overwrites)
    float phv[4][4], ggv[4][4];
#pragma unroll
    for (int i = 0; i < 4; ++i)
#pragma unroll
      for (int q = 0; q < 4; ++q) {
        int row = lg*4 + q, col = (w*4 + i)*16 + lr;
        phv[i][q] = bf2f(slabHG[hgIdx(row, col)]);
        ggv[i][q] = bf2f(slabHG[hgIdx(row, 512 + col)]);
      }
    barrier_lds();                         // S2: hd_l ready

    // ---- phase A: z|r ----
    i32x4 acc[8];
#pragma unroll
    for (int i = 0; i < 8; ++i) acc[i] = (i32x4){0, 0, 0, 0};
    // pinned units 0..3 (kt 0..1), no memory waits
    __builtin_amdgcn_s_setprio(1);
#pragma unroll
    for (int kt = 0; kt < 2; ++kt) {
      i32x4 af = hd_l[kt*64 + l];
#pragma unroll
      for (int hf = 0; hf < 2; ++hf)
#pragma unroll
        for (int i = 0; i < 4; ++i)
          acc[hf*4 + i] = __builtin_amdgcn_mfma_i32_16x16x64_i8(af, pinA[kt*2 + hf][i], acc[hf*4 + i], 0, 0, 0);
    }
    __builtin_amdgcn_s_setprio(0);
    // streamed units 4..15, depth-2 pipeline
    i32x4 af;
#pragma unroll
    for (int u = 4; u < 16; ++u) {
      asm volatile("s_waitcnt vmcnt(4)" ::: "memory");
      __builtin_amdgcn_sched_barrier(0);
      const signed char* buf = (u & 1) ? slot1 : slot0;
      if (!(u & 1)) af = hd_l[(u>>1)*64 + l];
      __builtin_amdgcn_s_setprio(1);
#pragma unroll
      for (int i = 0; i < 4; ++i) {
        i32x4 bfr = ((const i32x4*)buf)[i*64 + l];
        acc[(u&1)*4 + i] = __builtin_amdgcn_mfma_i32_16x16x64_i8(af, bfr, acc[(u&1)*4 + i], 0, 0, 0);
      }
      __builtin_amdgcn_s_setprio(0);
      __builtin_amdgcn_sched_barrier(0);
      if (u < 14)       STAGEA(u + 2);
      else if (u == 14) STAGEB(2);
      else              STAGEB(3);
    }

    // epilogue A: z -> regs; r -> slabHG (cols 0..511)
    float zreg[4][4];
#pragma unroll
    for (int i = 0; i < 4; ++i)
#pragma unroll
      for (int q = 0; q < 4; ++q) {
        int row = lg*4 + q, col = (w*4 + i)*16 + lr;
        float az = bf2f(pzr[0][i][q]) + (float)acc[i][q]   * zdq[i] * s;
        float ar = bf2f(pzr[1][i][q]) + (float)acc[4+i][q] * rdq[i] * s;
        zreg[i][q] = 1.f/(1.f + __expf(-az));
        slabHG[hgIdx(row, col)] = f2bf(1.f/(1.f + __expf(-ar)));
      }
    barrier_lds();                         // S3: r ready; phase-A hd_l reads done

    // a2 = hd*r quantized (same slot rewrite; |hd_q*r| <= 127)
    {
      const int k0 = w*64 + lg*16;
      bf16x8 r0v = *(const bf16x8*)&slabHG[hgIdx(lr, k0)];
      bf16x8 r1v = *(const bf16x8*)&slabHG[hgIdx(lr, k0 + 8)];
      i32x4 qw = hd_l[w*64 + l], nw;
#pragma unroll
      for (int d = 0; d < 4; ++d) {
        int word = qw[d], out = 0;
#pragma unroll
        for (int b = 0; b < 4; ++b) {
          int j = d*4 + b;
          int hq = (int)(signed char)((word >> (8*b)) & 0xFF);
          float rv = bf2f((unsigned short)(j < 8 ? r0v[j] : r1v[j-8]));
          float q = fminf(fmaxf(rintf((float)hq * rv), -127.f), 127.f);
          out |= ((int)q & 0xFF) << (8*b);
        }
        nw[d] = out;
      }
      hd_l[w*64 + l] = nw;
    }
    barrier_lds();                         // S4: a2 frags ready

    // ---- phase B: htilde ----
    i32x4 accB[4];
#pragma unroll
    for (int i = 0; i < 4; ++i) accB[i] = (i32x4){0, 0, 0, 0};
    // pinned units 0..1
    __builtin_amdgcn_s_setprio(1);
#pragma unroll
    for (int u = 0; u < 2; ++u) {
      i32x4 af2 = hd_l[u*64 + l];
#pragma unroll
      for (int i = 0; i < 4; ++i)
        accB[i] = __builtin_amdgcn_mfma_i32_16x16x64_i8(af2, pinB[u][i], accB[i], 0, 0, 0);
    }
    __builtin_amdgcn_s_setprio(0);
    // streamed units 2..7; tail stages HG(t+1), A4(t+1), A5(t+1)
#pragma unroll
    for (int u = 2; u < 8; ++u) {
      asm volatile("s_waitcnt vmcnt(4)" ::: "memory");
      __builtin_amdgcn_sched_barrier(0);
      const signed char* buf = (u & 1) ? slot1 : slot0;
      i32x4 af2 = hd_l[u*64 + l];
      __builtin_amdgcn_s_setprio(1);
#pragma unroll
      for (int i = 0; i < 4; ++i) {
        i32x4 bfr = ((const i32x4*)buf)[i*64 + l];
        accB[i] = __builtin_amdgcn_mfma_i32_16x16x64_i8(af2, bfr, accB[i], 0, 0, 0);
      }
      __builtin_amdgcn_s_setprio(0);
      __builtin_amdgcn_sched_barrier(0);
      if (u < 6)       STAGEB(u + 2);
      else if (u == 6) STAGEHG(PREnext);
      else             STAGEA(4);
    }
    STAGEA(5);

    // epilogue B: h update + block max|h| for next step's quant scale
    float mloc = 0.f;
#pragma unroll
    for (int i = 0; i < 4; ++i)
#pragma unroll
      for (int q = 0; q < 4; ++q) {
        int row = lg*4 + q, col = (w*4 + i)*16 + lr;
        float hval;
        if (row < na) {
          float ah = phv[i][q] + (float)accB[i][q] * hdq[i] * s;
          float e  = __expf(2.f*ah);
          float th = 1.f - 2.f/(e + 1.f);          // tanh, overflow-safe
          float hd = ggv[i][q] * hm[row][col];
          hval = hd + zreg[i][q]*(th - hd);
          hm[row][col] = hval;
        } else {
          hval = hm[row][col];
        }
        mloc = fmaxf(mloc, fabsf(hval));
      }
#pragma unroll
    for (int off = 32; off > 0; off >>= 1) mloc = fmaxf(mloc, __shfl_xor(mloc, off));
    if (l == 0) wmax[w] = fmaxf(mloc, 1e-20f);
  }

  asm volatile("s_waitcnt vmcnt(0)" ::: "memory");  // drain stray prefetches
  barrier_lds();
  for (int i = tid; i < 16*512; i += 512)
    h_st[(size_t)(r0 + (i>>9))*HH + (i&511)] = hm[i>>9][i&511];
  if (tid == 0) {
    float s = wmax[0];
#pragma unroll
    for (int i = 1; i < 8; ++i) s = fmaxf(s, wmax[i]);
    sbuf[blockIdx.x] = s;
  }
}

// ---------------------------------------------------------------------------
// K4: head: eval BatchNorm + decoder GEMV + log_softmax.
//   d_out = [output (256x64) | h_bn (256x512)] fp32
// ---------------------------------------------------------------------------
__global__ __launch_bounds__(64) void head_kernel(
    const float* __restrict__ h_state, const float* __restrict__ decW,
    const float* __restrict__ decb, const float* __restrict__ bnw,
    const float* __restrict__ bnb, float* __restrict__ out)
{
  int b = blockIdx.x, o = threadIdx.x;
  __shared__ float hbn[HH];
  const float s = rsqrtf(1.f + 1e-5f);
  for (int j = o; j < HH; j += 64)
    hbn[j] = h_state[(long)b*HH + j] * (bnw[j] * s) + bnb[j];
  __syncthreads();
  float acc = decb[o];
  for (int j = 0; j < HH; ++j) acc += hbn[j] * decW[j*OO + o];
  float mx = acc;
#pragma unroll
  for (int off = 32; off > 0; off >>= 1) mx = fmaxf(mx, __shfl_xor(mx, off));
  float ex = __expf(acc - mx);
  float sum = ex;
#pragma unroll
  for (int off = 32; off > 0; off >>= 1) sum += __shfl_xor(sum, off);
  out[(long)b*OO + o] = acc - mx - __logf(sum);
  for (int j = o; j < HH; j += 64)
    out[(long)BB*OO + (long)b*HH + j] = hbn[j];
}

// ---------------------------------------------------------------------------
extern "C" void kernel_launch(void* const* d_in, const int* in_sizes, int n_in,
                              void* d_out, int out_size, void* d_ws, size_t ws_size,
                              hipStream_t stream) {
  const float* x     = (const float*)d_in[0];
  const float* delta = (const float*)d_in[1];
  const float* mm    = (const float*)d_in[2];
  const float* xf    = (const float*)d_in[3];
  const int*   bs    = (const int*)  d_in[4];
  const float* W_r   = (const float*)d_in[5];
  const float* U_r   = (const float*)d_in[6];
  const float* V_r   = (const float*)d_in[7];
  const float* b_r   = (const float*)d_in[8];
  const float* W_z   = (const float*)d_in[9];
  const float* U_z   = (const float*)d_in[10];
  const float* V_z   = (const float*)d_in[11];
  const float* b_z   = (const float*)d_in[12];
  const float* W     = (const float*)d_in[13];
  const float* U     = (const float*)d_in[14];
  const float* V     = (const float*)d_in[15];
  const float* b     = (const float*)d_in[16];
  const float* Wgx   = (const float*)d_in[17];
  const float* bgx   = (const float*)d_in[18];
  const float* Wgh   = (const float*)d_in[19];
  const float* bgh   = (const float*)d_in[20];
  const float* decW  = (const float*)d_in[21];
  const float* decb  = (const float*)d_in[22];
  const float* bnw   = (const float*)d_in[23];
  const float* bnb   = (const float*)d_in[24];

  auto rnd = [](size_t v) { return (v + 255) & ~(size_t)255; };
  const size_t fixed_bytes = rnd((size_t)2048*256*2) + rnd(2048*4)
                           + rnd((size_t)512*1024) + rnd((size_t)256*1024)
                           + rnd(1536*4) + rnd(64)
                           + rnd((size_t)BB*HH*4);
  int TC = 0;
  const int cands[5] = {128, 64, 32, 16, 8};
  for (int i = 0; i < 5; ++i) {
    size_t need = fixed_bytes + rnd((size_t)BB*cands[i]*KK*2) + rnd((size_t)BB*cands[i]*NN*2);
    if (need <= ws_size) { TC = cands[i]; break; }
  }
  if (TC == 0) return;

  char* p = (char*)d_ws;
  auto alloc = [&](size_t bytes) { char* r = p; p += (bytes + 255) & ~(size_t)255; return r; };
  unsigned short* A_chunk = (unsigned short*)alloc((size_t)BB * TC * KK * 2);
  unsigned short* PREc    = (unsigned short*)alloc((size_t)BB * TC * NN * 2);
  unsigned short* BwT     = (unsigned short*)alloc((size_t)2048 * 256 * 2);
  float*          bias    = (float*)alloc(2048 * 4);
  int*            UzrQ    = (int*)alloc((size_t)512 * 1024);
  int*            UhQ     = (int*)alloc((size_t)256 * 1024);
  float*          uscale  = (float*)alloc(1536 * 4);
  float*          sbuf    = (float*)alloc(64);
  float*          h_st    = (float*)alloc((size_t)BB * HH * 4);

  prep_scales_kernel<<<6, 256, 0, stream>>>(U_z, U_r, U, uscale);
  prep_kernel<<<2824, 256, 0, stream>>>(W_z, V_z, b_z, W_r, V_r, b_r, W, V, b,
                                        Wgh, bgh, U_z, U_r, U, uscale,
                                        BwT, bias, UzrQ, UhQ);
  const int nch = TT / TC;
  for (int c = 0; c < nch; ++c) {
    int t0 = c * TC;
    build_A_kernel<<<BB*TC/8, 256, 0, stream>>>(x, delta, mm, xf, Wgx, bgx, bs,
                                                A_chunk, t0, TC);
    gemm1_kernel<<<(BB*TC/128)*16, 256, 0, stream>>>(A_chunk, BwT, bias, bs,
                                                     PREc, t0, TC);
    scan_kernel<<<16, 512, 0, stream>>>(PREc, (const signed char*)UzrQ,
                                        (const signed char*)UhQ, uscale, bs,
                                        h_st, sbuf, t0, TC);
  }
  head_kernel<<<256, 64, 0, stream>>>(h_st, decW, decb, bnw, bnb, (float*)d_out);
}

// Round 10
// 20828.293 us; speedup vs baseline: 1.2151x; 1.2151x over previous
//
#include <hip/hip_runtime.h>
#include <hip/hip_bf16.h>

typedef __attribute__((ext_vector_type(8))) short bf16x8;
typedef __attribute__((ext_vector_type(4))) float f32x4;
typedef __attribute__((ext_vector_type(4))) float fvec4;
typedef __attribute__((ext_vector_type(4))) unsigned short u16x4;
typedef __attribute__((ext_vector_type(4))) int i32x4;
typedef __attribute__((ext_vector_type(2))) unsigned int u32x2;

#define DEVI __device__ __forceinline__

constexpr int BB = 256, TT = 1024, FF = 128, HH = 512, OO = 64;
constexpr int KK = 256;    // fused input width [x_imp | m]
constexpr int NN = 2048;   // fused gate width  [z | r | htilde | gamma_h]

DEVI unsigned short f2bf(float x) {
  unsigned int u = __float_as_uint(x);
  u += 0x7FFFu + ((u >> 16) & 1u);          // RNE
  return (unsigned short)(u >> 16);
}
DEVI float bf2f(unsigned short s) {
  return __uint_as_float(((unsigned int)s) << 16);
}

DEVI void gload16(const void* g, void* lds) {
  __builtin_amdgcn_global_load_lds(
      (const __attribute__((address_space(1))) void*)g,
      (__attribute__((address_space(3))) void*)lds, 16, 0, 0);
}

DEVI void barrier_lds() {       // raw barrier: waits LDS ops only, vmcnt SURVIVES
  asm volatile("s_waitcnt lgkmcnt(0)" ::: "memory");
  __builtin_amdgcn_s_barrier();
  __builtin_amdgcn_sched_barrier(0);
}

// slabHG address swizzle (shorts): involution within a row, applied on BOTH
// the stage source and every read/write.
DEVI int hgIdx(int row, int c) { return row*1024 + (c ^ ((row & 7) << 3)); }

// ---------------------------------------------------------------------------
// K0a: per-column scales s_n = max_k |U[k][n]|  (z:0..511, r:512..1023, h:1024..1535)
// ---------------------------------------------------------------------------
__global__ __launch_bounds__(256) void prep_scales_kernel(
    const float* __restrict__ U_z, const float* __restrict__ U_r,
    const float* __restrict__ Uh, float* __restrict__ uscale)
{
  int n = blockIdx.x * 256 + threadIdx.x;
  if (n >= 1536) return;
  const float* src = (n < 512) ? U_z : (n < 1024) ? U_r : Uh;
  int col = n & 511;
  float s = 0.f;
  for (int k = 0; k < HH; ++k) s = fmaxf(s, fabsf(src[k*HH + col]));
  uscale[n] = fmaxf(s, 1e-30f);
}

// ---------------------------------------------------------------------------
// K0b: pack weights.
//   BwT [2048][256] bf16, bias[2048] f32 (as before)
//   UzrN u4 [16 u][8 wv][4 i][64 l][2 c] words: unit u = kt*2+half
//     (half 0 = U_z, 1 = U_r). Word (…,c): nibble p holds value
//     q+8 at j = c*8 + (p&1)*4 + (p>>1), k = kt*64 + (l>>4)*16 + j,
//     col = (wv*4+i)*16 + (l&15), q = clamp(round(U/s_col*7), -7, 7).
//     Permuted so unpack is W&0x0F0F0F0F / (W>>4)&0x0F0F0F0F.
//   UhQ i8 [8 kt][32 nt][64 l][16 j] (unchanged, per-column scale /127)
// ---------------------------------------------------------------------------
__global__ __launch_bounds__(256) void prep_kernel(
    const float* __restrict__ W_z, const float* __restrict__ V_z, const float* __restrict__ b_z,
    const float* __restrict__ W_r, const float* __restrict__ V_r, const float* __restrict__ b_r,
    const float* __restrict__ Wh,  const float* __restrict__ Vh,  const float* __restrict__ bh,
    const float* __restrict__ Wgh, const float* __restrict__ bgh,
    const float* __restrict__ U_z, const float* __restrict__ U_r, const float* __restrict__ Uh,
    const float* __restrict__ uscale,
    unsigned short* __restrict__ BwT, float* __restrict__ bias,
    unsigned int* __restrict__ UzrN, int* __restrict__ UhQ)
{
  int idx = blockIdx.x * 256 + threadIdx.x;
  if (idx < 524288) {                       // BwT
    int n = idx >> 8, k = idx & 255;
    float v;
    if (n < 512)       { int h = n;        v = (k < 128) ? W_z[k*HH + h] : -V_z[(k-128)*HH + h]; }
    else if (n < 1024) { int h = n - 512;  v = (k < 128) ? W_r[k*HH + h] : -V_r[(k-128)*HH + h]; }
    else if (n < 1536) { int h = n - 1024; v = (k < 128) ? Wh [k*HH + h] : -Vh [(k-128)*HH + h]; }
    else               { int h = n - 1536; v = (k < 128) ? 0.f : Wgh[(k-128)*HH + h]; }
    BwT[n*256 + k] = f2bf(v);
    return;
  }
  idx -= 524288;
  if (idx < 2048) {                         // bias
    int n = idx; float v;
    if (n < 512)       { float s = b_z[n];      for (int f = 0; f < FF; ++f) s += V_z[f*HH + n];        v = s; }
    else if (n < 1024) { int h = n-512;  float s = b_r[h]; for (int f = 0; f < FF; ++f) s += V_r[f*HH + h]; v = s; }
    else if (n < 1536) { int h = n-1024; float s = bh[h];  for (int f = 0; f < FF; ++f) s += Vh[f*HH + h];  v = s; }
    else               { v = bgh[n-1536]; }
    bias[n] = v;
    return;
  }
  idx -= 2048;
  if (idx < 65536) {                        // UzrN words (i4, permuted, +8)
    int c  = idx & 1;
    int l  = (idx >> 1) & 63;
    int i  = (idx >> 7) & 3;
    int wv = (idx >> 9) & 7;
    int u  = idx >> 12;                    // 0..15
    int kt = u >> 1, half = u & 1;
    int col = (wv*4 + i)*16 + (l & 15);
    const float* src = half ? U_r : U_z;
    float sc = 7.f / uscale[half*512 + col];
    unsigned int word = 0;
#pragma unroll
    for (int p = 0; p < 8; ++p) {
      int j = c*8 + (p & 1)*4 + (p >> 1);
      int k = kt*64 + (l >> 4)*16 + j;
      float q = fminf(fmaxf(rintf(src[k*HH + col] * sc), -7.f), 7.f);
      unsigned int uq = (unsigned int)((int)q + 8);
      word |= (uq & 0xF) << (4*p);
    }
    UzrN[idx] = word;
    return;
  }
  idx -= 65536;
  if (idx < 65536) {                        // UhQ words (i8)
    int j0 = (idx & 3) * 4;
    int l  = (idx >> 2) & 63;
    int nt = (idx >> 8) & 31;
    int kt = idx >> 13;
    int col = nt*16 + (l & 15);
    float sc = 127.f / uscale[1024 + col];
    int word = 0;
#pragma unroll
    for (int b = 0; b < 4; ++b) {
      int k = kt*64 + (l >> 4)*16 + j0 + b;
      float q = fminf(fmaxf(rintf(Uh[k*HH + col] * sc), -127.f), 127.f);
      word |= ((int)q & 0xFF) << (8*b);
    }
    UhQ[idx] = word;
  }
}

// ---------------------------------------------------------------------------
// K1: imputation + fused A chunk [B*TC][256] bf16 = [x_imp | m]
// ---------------------------------------------------------------------------
__global__ __launch_bounds__(256) void build_A_kernel(
    const float* __restrict__ x, const float* __restrict__ delta,
    const float* __restrict__ mm, const float* __restrict__ xf,
    const float* __restrict__ Wgx, const float* __restrict__ bgx,
    const int* __restrict__ bs, unsigned short* __restrict__ A,
    int t0, int TC)
{
  int blk = blockIdx.x;
  int row8 = blk * 8;
  int b0  = row8 / TC;
  int tl0 = row8 % TC;
  if (b0 >= bs[t0 + tl0]) return;
  int tid = threadIdx.x;
  int rl = row8 + (tid >> 5);
  int tc = tl0 + (tid >> 5);
  long gi = ((long)b0*TT + t0 + tc) * 32 + (tid & 31);
  int f0 = (tid & 31) * 4;
  fvec4 xv = ((const fvec4*)x)[gi];
  fvec4 dv = ((const fvec4*)delta)[gi];
  fvec4 mv = ((const fvec4*)mm)[gi];
  fvec4 fv = ((const fvec4*)xf)[gi];
  unsigned short ox[4], om[4];
#pragma unroll
  for (int j = 0; j < 4; ++j) {
    float g  = __expf(-fmaxf(dv[j]*Wgx[f0+j] + bgx[f0+j], 0.f));
    float xr = g*fv[j] + (1.f - g)*0.001f;
    float xi = (mv[j] > 0.5f) ? xr : xv[j];
    ox[j] = f2bf(xi); om[j] = f2bf(mv[j]);
  }
  *(u16x4*)(A + (long)rl*KK + f0)       = (u16x4){ox[0], ox[1], ox[2], ox[3]};
  *(u16x4*)(A + (long)rl*KK + 128 + f0) = (u16x4){om[0], om[1], om[2], om[3]};
}

// ---------------------------------------------------------------------------
// K2: chunk GEMM  PRE[m][n] = A[m][:] @ Bw[:,n] + bias[n]  (bf16 MFMA, K=256)
// ---------------------------------------------------------------------------
__global__ __launch_bounds__(256) void gemm1_kernel(
    const unsigned short* __restrict__ A, const unsigned short* __restrict__ BwT,
    const float* __restrict__ bias, const int* __restrict__ bs,
    unsigned short* __restrict__ PRE, int t0, int TC)
{
  int blk = blockIdx.x;
  int nt = blk & 15;
  int mt = blk >> 4;
  {
    int m0 = mt * 128;
    int b_ = m0 / TC;
    int bcheck = (TC >= 128) ? bs[t0 + (m0 % TC)] : bs[t0];
    if (b_ >= bcheck) return;
  }
  int tid = threadIdx.x;
  int w = tid >> 6, l = tid & 63;
  int wm = w >> 1, wn = w & 1;
  int lr = l & 15, lg = l >> 4;
  int m_base = mt*128 + wm*64;
  int n_base = nt*128 + wn*64;
  const unsigned short* Aptr = A   + (long)(m_base + lr)*KK + lg*8;
  const unsigned short* Bptr = BwT + (long)(n_base + lr)*KK + lg*8;
  f32x4 acc[4][4];
#pragma unroll
  for (int i = 0; i < 4; ++i)
#pragma unroll
    for (int j = 0; j < 4; ++j) acc[i][j] = (f32x4){0.f, 0.f, 0.f, 0.f};

#pragma unroll
  for (int kt = 0; kt < 8; ++kt) {
    bf16x8 af[4], bfr[4];
#pragma unroll
    for (int i = 0; i < 4; ++i) af[i]  = *(const bf16x8*)(Aptr + (long)i*16*KK + kt*32);
#pragma unroll
    for (int i = 0; i < 4; ++i) bfr[i] = *(const bf16x8*)(Bptr + (long)i*16*KK + kt*32);
#pragma unroll
    for (int ms = 0; ms < 4; ++ms)
#pragma unroll
      for (int ns = 0; ns < 4; ++ns)
        acc[ms][ns] = __builtin_amdgcn_mfma_f32_16x16x32_bf16(af[ms], bfr[ns], acc[ms][ns], 0, 0, 0);
  }
#pragma unroll
  for (int ms = 0; ms < 4; ++ms) {
    int gm0 = m_base + ms*16 + lg*4;
#pragma unroll
    for (int ns = 0; ns < 4; ++ns) {
      int gn = n_base + ns*16 + lr;
      float bv = bias[gn];
      bool is_gamma = (gn >= 1536);
#pragma unroll
      for (int q = 0; q < 4; ++q) {
        float v = acc[ms][ns][q] + bv;
        if (is_gamma) v = __expf(-fmaxf(v, 0.f));
        PRE[(long)(gm0 + q)*NN + gn] = f2bf(v);
      }
    }
  }
}

// ---------------------------------------------------------------------------
// K3: sequential scan, 16 blocks x 512 threads (8 waves), i8 MFMA (K=64).
//   z/r U streamed as int4 nibbles (+8 offset, 256 KB/step) via per-lane
//   VGPR loads with register double-buffer + 3-op unpack; exact offset
//   correction via rowsum(hd_q). Uh (i8) + HG keep the depth-2
//   global_load_lds pipeline with counted vmcnt. Stream: 584 KB/step.
// ---------------------------------------------------------------------------
__global__ __launch_bounds__(512, 2) void scan_kernel(
    const unsigned short* __restrict__ PRE,
    const unsigned int* __restrict__ UzrN,
    const signed char* __restrict__ UhQ,
    const float* __restrict__ uscale,
    const int* __restrict__ bs,
    float* __restrict__ h_st,
    float* __restrict__ sbuf,
    int t0, int TC)
{
  __shared__ __align__(16) signed char Ubuf[8][2][4096];   // 64 KB per-wave dbuf (Uh)
  __shared__ __align__(16) i32x4 hd_l[8*64];               // 8 KB hd / a2 frags
  __shared__ __align__(16) unsigned short slabHG[16*1024]; // 32 KB [row][htld|r : gamma]
  __shared__ float hm[16][524];                            // 33.5 KB h master
  __shared__ int hsumW[8][16];                             // rowsum partials
  __shared__ float wmax[8];

  const int tid = threadIdx.x;
  const int r0 = blockIdx.x * 16;
  if (t0 > 0 && bs[t0] <= r0) return;

  const int w = tid >> 6, l = tid & 63, lr = l & 15, lg = l >> 4;
  const size_t rowStr = (size_t)TC * NN;

  signed char* slot0 = &Ubuf[w][0][0];
  signed char* slot1 = &Ubuf[w][1][0];

  auto STAGEB = [&](int u) {   // Uh unit: kt=u, tiles {4w..4w+3}
    const signed char* src = UhQ + ((size_t)((u*32 + w*4)*64) + l)*16;
    signed char* dst = (u & 1) ? slot1 : slot0;
#pragma unroll
    for (int i = 0; i < 4; ++i) gload16(src + (size_t)i*1024, dst + i*1024);
  };
  auto STAGEHG = [&](const unsigned short* PREn) {  // htilde+gamma halves, swizzled source
#pragma unroll
    for (int j = 0; j < 4; ++j) {
      int idx = w*4 + j;
      int row = idx >> 1;
      int phys = (idx & 1)*512 + l*8;
      int logi = phys ^ ((row & 7) << 3);
      const unsigned short* src = PREn + (size_t)row*rowStr + 1024 + logi;
      gload16(src, &slabHG[idx*512]);
    }
  };
  auto LOADZR = [&](int u, u32x2* d) {   // z/r unit u: 4 tiles x 8B per thread
#pragma unroll
    for (int i = 0; i < 4; ++i)
      d[i] = ((const u32x2*)UzrN)[((u*8 + w)*4 + i)*64 + l];
  };

  // per-thread dequant constants
  float zdq[4], rdq[4], hdq[4];
#pragma unroll
  for (int i = 0; i < 4; ++i) {
    int c = (w*4 + i)*16 + lr;
    zdq[i] = uscale[c]        * (1.f/889.f);    // 7 * 127
    rdq[i] = uscale[512 + c]  * (1.f/889.f);
    hdq[i] = uscale[1024 + c] * (1.f/16129.f);  // 127 * 127
  }
  if (tid < 8) wmax[tid] = (t0 == 0) ? 1e-20f : sbuf[blockIdx.x];

  if (t0 == 0) {
    for (int i = tid; i < 16*512; i += 512) hm[i>>9][i&511] = 0.f;
  } else {
    for (int i = tid; i < 16*512; i += 512)
      hm[i>>9][i&511] = h_st[(size_t)(r0 + (i>>9))*HH + (i&511)];
  }
  asm volatile("s_waitcnt vmcnt(0)" ::: "memory");  // hm loads fully done
  __builtin_amdgcn_sched_barrier(0);

  // prologue staging: HG(step 0), B0, B1  (12 loads outstanding)
  STAGEHG(PRE + (size_t)r0*TC*NN);
  STAGEB(0); STAGEB(1);

  for (int tc = 0; tc < TC; ++tc) {
    const int bsv = bs[t0 + tc];
    if (bsv <= r0) break;                  // descending bs: done forever
    const int na = min(16, bsv - r0);
    const unsigned short* PREstep = PRE + ((size_t)r0*TC + tc)*NN;
    const unsigned short* PREnext = PREstep + NN;

    barrier_lds();                         // S1: prev hm + wmax writes visible
    asm volatile("s_waitcnt vmcnt(8)" ::: "memory");  // HG landed; B0,B1 fly
    __builtin_amdgcn_sched_barrier(0);

    // dynamic quant scale for hd (exact bound: |hd| <= max|h| = s)
    float s = wmax[0];
#pragma unroll
    for (int i = 1; i < 8; ++i) s = fmaxf(s, wmax[i]);
    const float qs = 127.f / s;

    // pz/pr clump (VGPR loads, consumed in epilogue A)
    unsigned short pzr[2][4][4];
#pragma unroll
    for (int i = 0; i < 4; ++i)
#pragma unroll
      for (int q = 0; q < 4; ++q) {
        int row = lg*4 + q, col = (w*4 + i)*16 + lr;
        const unsigned short* pb = PREstep + (size_t)row*rowStr + col;
        pzr[0][i][q] = pb[0];
        pzr[1][i][q] = pb[512];
      }

    // prefetch z/r units 0,1 into registers
    u32x2 inW0[4], inW1[4];
    LOADZR(0, inW0);
    LOADZR(1, inW1);

    // hd build (kt = w): quantize (act? gamma*h : h) to i8 frags + rowsum
    {
      const int k0 = w*64 + lg*16;
      const bool act = lr < na;
      bf16x8 g0 = *(const bf16x8*)&slabHG[hgIdx(lr, 512 + k0)];
      bf16x8 g1 = *(const bf16x8*)&slabHG[hgIdx(lr, 512 + k0 + 8)];
      i32x4 qw;
      int psum = 0;
#pragma unroll
      for (int d = 0; d < 4; ++d) {
        int word = 0;
#pragma unroll
        for (int b = 0; b < 4; ++b) {
          int j = d*4 + b;
          float h  = hm[lr][k0 + j];
          float gv = bf2f((unsigned short)(j < 8 ? g0[j] : g1[j-8]));
          float hd = act ? gv*h : h;
          float q  = fminf(fmaxf(rintf(hd*qs), -127.f), 127.f);
          int qi = (int)q;
          psum += qi;
          word |= (qi & 0xFF) << (8*b);
        }
        qw[d] = word;
      }
      hd_l[w*64 + l] = qw;
      psum += __shfl_xor(psum, 16);
      psum += __shfl_xor(psum, 32);
      if (lg == 0) hsumW[w][lr] = psum;    // wave w's k-range [64w, 64w+64)
    }

    // hoist htilde-preact + gamma for my output cells (before r overwrites)
    float phv[4][4], ggv[4][4];
#pragma unroll
    for (int i = 0; i < 4; ++i)
#pragma unroll
      for (int q = 0; q < 4; ++q) {
        int row = lg*4 + q, col = (w*4 + i)*16 + lr;
        phv[i][q] = bf2f(slabHG[hgIdx(row, col)]);
        ggv[i][q] = bf2f(slabHG[hgIdx(row, 512 + col)]);
      }
    barrier_lds();                         // S2: hd_l + hsumW ready

    // ---- phase A: z|r, 16 units, register-streamed i4 ----
    i32x4 acc[8];
#pragma unroll
    for (int i = 0; i < 8; ++i) acc[i] = (i32x4){0, 0, 0, 0};
    i32x4 af;
#pragma unroll
    for (int u = 0; u < 16; ++u) {
      if (!(u & 1)) af = hd_l[(u>>1)*64 + l];
      u32x2* inw = (u & 1) ? inW1 : inW0;
      __builtin_amdgcn_s_setprio(1);
#pragma unroll
      for (int i = 0; i < 4; ++i) {
        unsigned int W0 = inw[i][0], W1 = inw[i][1];
        i32x4 bfr;
        bfr[0] = (int)(W0 & 0x0F0F0F0Fu);
        bfr[1] = (int)((W0 >> 4) & 0x0F0F0F0Fu);
        bfr[2] = (int)(W1 & 0x0F0F0F0Fu);
        bfr[3] = (int)((W1 >> 4) & 0x0F0F0F0Fu);
        acc[(u&1)*4 + i] = __builtin_amdgcn_mfma_i32_16x16x64_i8(af, bfr, acc[(u&1)*4 + i], 0, 0, 0);
      }
      __builtin_amdgcn_s_setprio(0);
      if (u < 14) LOADZR(u + 2, (u & 1) ? inW1 : inW0);
    }

    // epilogue A: offset-correct, z -> regs; r -> slabHG (cols 0..511)
    int rsum[4];
#pragma unroll
    for (int q = 0; q < 4; ++q) {
      int row = lg*4 + q, t = 0;
#pragma unroll
      for (int w2 = 0; w2 < 8; ++w2) t += hsumW[w2][row];
      rsum[q] = t * 8;
    }
    float zreg[4][4];
#pragma unroll
    for (int i = 0; i < 4; ++i)
#pragma unroll
      for (int q = 0; q < 4; ++q) {
        int row = lg*4 + q, col = (w*4 + i)*16 + lr;
        float az = bf2f(pzr[0][i][q]) + (float)(acc[i][q]   - rsum[q]) * zdq[i] * s;
        float ar = bf2f(pzr[1][i][q]) + (float)(acc[4+i][q] - rsum[q]) * rdq[i] * s;
        zreg[i][q] = 1.f/(1.f + __expf(-az));
        slabHG[hgIdx(row, col)] = f2bf(1.f/(1.f + __expf(-ar)));
      }
    barrier_lds();                         // S3: r ready; phase-A hd_l reads done

    // a2 = hd*r quantized (same slot rewrite; |hd_q*r| <= 127)
    {
      const int k0 = w*64 + lg*16;
      bf16x8 r0v = *(const bf16x8*)&slabHG[hgIdx(lr, k0)];
      bf16x8 r1v = *(const bf16x8*)&slabHG[hgIdx(lr, k0 + 8)];
      i32x4 qw = hd_l[w*64 + l], nw;
#pragma unroll
      for (int d = 0; d < 4; ++d) {
        int word = qw[d], out = 0;
#pragma unroll
        for (int b = 0; b < 4; ++b) {
          int j = d*4 + b;
          int hq = (int)(signed char)((word >> (8*b)) & 0xFF);
          float rv = bf2f((unsigned short)(j < 8 ? r0v[j] : r1v[j-8]));
          float q = fminf(fmaxf(rintf((float)hq * rv), -127.f), 127.f);
          out |= ((int)q & 0xFF) << (8*b);
        }
        nw[d] = out;
      }
      hd_l[w*64 + l] = nw;
    }
    barrier_lds();                         // S4: a2 frags ready

    // ---- phase B: htilde, 8 units (i8, glds depth-2) ----
    // FIFO at this point: only B/HG stages (all older VGPR loads retired
    // by their compiler-inserted waits in phase A) -> counts are exact.
    i32x4 accB[4];
#pragma unroll
    for (int i = 0; i < 4; ++i) accB[i] = (i32x4){0, 0, 0, 0};
#pragma unroll
    for (int u = 0; u < 8; ++u) {
      asm volatile("s_waitcnt vmcnt(4)" ::: "memory");
      __builtin_amdgcn_sched_barrier(0);
      const signed char* buf = (u & 1) ? slot1 : slot0;
      i32x4 af2 = hd_l[u*64 + l];
      __builtin_amdgcn_s_setprio(1);
#pragma unroll
      for (int i = 0; i < 4; ++i) {
        i32x4 bfr = ((const i32x4*)buf)[i*64 + l];
        accB[i] = __builtin_amdgcn_mfma_i32_16x16x64_i8(af2, bfr, accB[i], 0, 0, 0);
      }
      __builtin_amdgcn_s_setprio(0);
      __builtin_amdgcn_sched_barrier(0);
      if (u < 6)       STAGEB(u + 2);
      else if (u == 6) STAGEHG(PREnext);
      else             STAGEB(0);          // next step's B0 (time-invariant)
    }
    STAGEB(1);                             // next step's B1

    // epilogue B: h update + block max|h| for next step's quant scale
    float mloc = 0.f;
#pragma unroll
    for (int i = 0; i < 4; ++i)
#pragma unroll
      for (int q = 0; q < 4; ++q) {
        int row = lg*4 + q, col = (w*4 + i)*16 + lr;
        float hval;
        if (row < na) {
          float ah = phv[i][q] + (float)accB[i][q] * hdq[i] * s;
          float e  = __expf(2.f*ah);
          float th = 1.f - 2.f/(e + 1.f);          // tanh, overflow-safe
          float hd = ggv[i][q] * hm[row][col];
          hval = hd + zreg[i][q]*(th - hd);
          hm[row][col] = hval;
        } else {
          hval = hm[row][col];
        }
        mloc = fmaxf(mloc, fabsf(hval));
      }
#pragma unroll
    for (int off = 32; off > 0; off >>= 1) mloc = fmaxf(mloc, __shfl_xor(mloc, off));
    if (l == 0) wmax[w] = fmaxf(mloc, 1e-20f);
  }

  asm volatile("s_waitcnt vmcnt(0)" ::: "memory");  // drain stray prefetches
  barrier_lds();
  for (int i = tid; i < 16*512; i += 512)
    h_st[(size_t)(r0 + (i>>9))*HH + (i&511)] = hm[i>>9][i&511];
  if (tid == 0) {
    float s = wmax[0];
#pragma unroll
    for (int i = 1; i < 8; ++i) s = fmaxf(s, wmax[i]);
    sbuf[blockIdx.x] = s;
  }
}

// ---------------------------------------------------------------------------
// K4: head: eval BatchNorm + decoder GEMV + log_softmax.
//   d_out = [output (256x64) | h_bn (256x512)] fp32
// ---------------------------------------------------------------------------
__global__ __launch_bounds__(64) void head_kernel(
    const float* __restrict__ h_state, const float* __restrict__ decW,
    const float* __restrict__ decb, const float* __restrict__ bnw,
    const float* __restrict__ bnb, float* __restrict__ out)
{
  int b = blockIdx.x, o = threadIdx.x;
  __shared__ float hbn[HH];
  const float s = rsqrtf(1.f + 1e-5f);
  for (int j = o; j < HH; j += 64)
    hbn[j] = h_state[(long)b*HH + j] * (bnw[j] * s) + bnb[j];
  __syncthreads();
  float acc = decb[o];
  for (int j = 0; j < HH; ++j) acc += hbn[j] * decW[j*OO + o];
  float mx = acc;
#pragma unroll
  for (int off = 32; off > 0; off >>= 1) mx = fmaxf(mx, __shfl_xor(mx, off));
  float ex = __expf(acc - mx);
  float sum = ex;
#pragma unroll
  for (int off = 32; off > 0; off >>= 1) sum += __shfl_xor(sum, off);
  out[(long)b*OO + o] = acc - mx - __logf(sum);
  for (int j = o; j < HH; j += 64)
    out[(long)BB*OO + (long)b*HH + j] = hbn[j];
}

// ---------------------------------------------------------------------------
extern "C" void kernel_launch(void* const* d_in, const int* in_sizes, int n_in,
                              void* d_out, int out_size, void* d_ws, size_t ws_size,
                              hipStream_t stream) {
  const float* x     = (const float*)d_in[0];
  const float* delta = (const float*)d_in[1];
  const float* mm    = (const float*)d_in[2];
  const float* xf    = (const float*)d_in[3];
  const int*   bs    = (const int*)  d_in[4];
  const float* W_r   = (const float*)d_in[5];
  const float* U_r   = (const float*)d_in[6];
  const float* V_r   = (const float*)d_in[7];
  const float* b_r   = (const float*)d_in[8];
  const float* W_z   = (const float*)d_in[9];
  const float* U_z   = (const float*)d_in[10];
  const float* V_z   = (const float*)d_in[11];
  const float* b_z   = (const float*)d_in[12];
  const float* W     = (const float*)d_in[13];
  const float* U     = (const float*)d_in[14];
  const float* V     = (const float*)d_in[15];
  const float* b     = (const float*)d_in[16];
  const float* Wgx   = (const float*)d_in[17];
  const float* bgx   = (const float*)d_in[18];
  const float* Wgh   = (const float*)d_in[19];
  const float* bgh   = (const float*)d_in[20];
  const float* decW  = (const float*)d_in[21];
  const float* decb  = (const float*)d_in[22];
  const float* bnw   = (const float*)d_in[23];
  const float* bnb   = (const float*)d_in[24];

  auto rnd = [](size_t v) { return (v + 255) & ~(size_t)255; };
  const size_t fixed_bytes = rnd((size_t)2048*256*2) + rnd(2048*4)
                           + rnd((size_t)256*1024) + rnd((size_t)256*1024)
                           + rnd(1536*4) + rnd(64)
                           + rnd((size_t)BB*HH*4);
  int TC = 0;
  const int cands[5] = {128, 64, 32, 16, 8};
  for (int i = 0; i < 5; ++i) {
    size_t need = fixed_bytes + rnd((size_t)BB*cands[i]*KK*2) + rnd((size_t)BB*cands[i]*NN*2);
    if (need <= ws_size) { TC = cands[i]; break; }
  }
  if (TC == 0) return;

  char* p = (char*)d_ws;
  auto alloc = [&](size_t bytes) { char* r = p; p += (bytes + 255) & ~(size_t)255; return r; };
  unsigned short* A_chunk = (unsigned short*)alloc((size_t)BB * TC * KK * 2);
  unsigned short* PREc    = (unsigned short*)alloc((size_t)BB * TC * NN * 2);
  unsigned short* BwT     = (unsigned short*)alloc((size_t)2048 * 256 * 2);
  float*          bias    = (float*)alloc(2048 * 4);
  unsigned int*   UzrN    = (unsigned int*)alloc((size_t)256 * 1024);
  int*            UhQ     = (int*)alloc((size_t)256 * 1024);
  float*          uscale  = (float*)alloc(1536 * 4);
  float*          sbuf    = (float*)alloc(64);
  float*          h_st    = (float*)alloc((size_t)BB * HH * 4);

  prep_scales_kernel<<<6, 256, 0, stream>>>(U_z, U_r, U, uscale);
  prep_kernel<<<2568, 256, 0, stream>>>(W_z, V_z, b_z, W_r, V_r, b_r, W, V, b,
                                        Wgh, bgh, U_z, U_r, U, uscale,
                                        BwT, bias, UzrN, UhQ);
  const int nch = TT / TC;
  for (int c = 0; c < nch; ++c) {
    int t0 = c * TC;
    build_A_kernel<<<BB*TC/8, 256, 0, stream>>>(x, delta, mm, xf, Wgx, bgx, bs,
                                                A_chunk, t0, TC);
    gemm1_kernel<<<(BB*TC/128)*16, 256, 0, stream>>>(A_chunk, BwT, bias, bs,
                                                     PREc, t0, TC);
    scan_kernel<<<16, 512, 0, stream>>>(PREc, UzrN, (const signed char*)UhQ,
                                        uscale, bs, h_st, sbuf, t0, TC);
  }
  head_kernel<<<256, 64, 0, stream>>>(h_st, decW, decb, bnw, bnb, (float*)d_out);
}

// Round 11
// 19582.986 us; speedup vs baseline: 1.2924x; 1.0636x over previous
//
#include <hip/hip_runtime.h>
#include <hip/hip_bf16.h>

typedef __attribute__((ext_vector_type(8))) short bf16x8;
typedef __attribute__((ext_vector_type(4))) float f32x4;
typedef __attribute__((ext_vector_type(4))) float fvec4;
typedef __attribute__((ext_vector_type(4))) unsigned short u16x4;
typedef __attribute__((ext_vector_type(4))) int i32x4;
typedef __attribute__((ext_vector_type(2))) unsigned int u32x2;

#define DEVI __device__ __forceinline__

constexpr int BB = 256, TT = 1024, FF = 128, HH = 512, OO = 64;
constexpr int KK = 256;    // fused input width [x_imp | m]
constexpr int NN = 2048;   // fused gate width  [z | r | htilde | gamma_h]

DEVI unsigned short f2bf(float x) {
  unsigned int u = __float_as_uint(x);
  u += 0x7FFFu + ((u >> 16) & 1u);          // RNE
  return (unsigned short)(u >> 16);
}
DEVI float bf2f(unsigned short s) {
  return __uint_as_float(((unsigned int)s) << 16);
}

DEVI void gload16(const void* g, void* lds) {
  __builtin_amdgcn_global_load_lds(
      (const __attribute__((address_space(1))) void*)g,
      (__attribute__((address_space(3))) void*)lds, 16, 0, 0);
}

DEVI void barrier_lds() {       // raw barrier: waits LDS ops only, vmcnt SURVIVES
  asm volatile("s_waitcnt lgkmcnt(0)" ::: "memory");
  __builtin_amdgcn_s_barrier();
  __builtin_amdgcn_sched_barrier(0);
}

// slabHG address swizzle (shorts): involution within a row, applied on BOTH
// the stage source and every read/write.
DEVI int hgIdx(int row, int c) { return row*1024 + (c ^ ((row & 7) << 3)); }

// ---------------------------------------------------------------------------
// K0a: per-column scales s_n = max_k |U[k][n]|  (z:0..511, r:512..1023, h:1024..1535)
// ---------------------------------------------------------------------------
__global__ __launch_bounds__(256) void prep_scales_kernel(
    const float* __restrict__ U_z, const float* __restrict__ U_r,
    const float* __restrict__ Uh, float* __restrict__ uscale)
{
  int n = blockIdx.x * 256 + threadIdx.x;
  if (n >= 1536) return;
  const float* src = (n < 512) ? U_z : (n < 1024) ? U_r : Uh;
  int col = n & 511;
  float s = 0.f;
  for (int k = 0; k < HH; ++k) s = fmaxf(s, fabsf(src[k*HH + col]));
  uscale[n] = fmaxf(s, 1e-30f);
}

// ---------------------------------------------------------------------------
// K0b: pack weights.
//   BwT [2048][256] bf16, bias[2048] f32 (as before)
//   UzrN u4 [16 u][8 wv][4 i][64 l][2 c] words (unit u = kt*2+half; half0=Uz)
//   UhN  u4 [ 8 u][8 wv][4 i][64 l][2 c] words (unit u = kt)
//   Word (…,c): nibble p = value q+8 at j = c*8 + (p&1)*4 + (p>>1),
//   k = base_k + (l>>4)*16 + j, col = (wv*4+i)*16 + (l&15),
//   q = clamp(round(U/s_col*7), -7, 7). Unpack = W&0x0F0F0F0F / (W>>4)&…
// ---------------------------------------------------------------------------
__global__ __launch_bounds__(256) void prep_kernel(
    const float* __restrict__ W_z, const float* __restrict__ V_z, const float* __restrict__ b_z,
    const float* __restrict__ W_r, const float* __restrict__ V_r, const float* __restrict__ b_r,
    const float* __restrict__ Wh,  const float* __restrict__ Vh,  const float* __restrict__ bh,
    const float* __restrict__ Wgh, const float* __restrict__ bgh,
    const float* __restrict__ U_z, const float* __restrict__ U_r, const float* __restrict__ Uh,
    const float* __restrict__ uscale,
    unsigned short* __restrict__ BwT, float* __restrict__ bias,
    unsigned int* __restrict__ UzrN, unsigned int* __restrict__ UhN)
{
  int idx = blockIdx.x * 256 + threadIdx.x;
  if (idx < 524288) {                       // BwT
    int n = idx >> 8, k = idx & 255;
    float v;
    if (n < 512)       { int h = n;        v = (k < 128) ? W_z[k*HH + h] : -V_z[(k-128)*HH + h]; }
    else if (n < 1024) { int h = n - 512;  v = (k < 128) ? W_r[k*HH + h] : -V_r[(k-128)*HH + h]; }
    else if (n < 1536) { int h = n - 1024; v = (k < 128) ? Wh [k*HH + h] : -Vh [(k-128)*HH + h]; }
    else               { int h = n - 1536; v = (k < 128) ? 0.f : Wgh[(k-128)*HH + h]; }
    BwT[n*256 + k] = f2bf(v);
    return;
  }
  idx -= 524288;
  if (idx < 2048) {                         // bias
    int n = idx; float v;
    if (n < 512)       { float s = b_z[n];      for (int f = 0; f < FF; ++f) s += V_z[f*HH + n];        v = s; }
    else if (n < 1024) { int h = n-512;  float s = b_r[h]; for (int f = 0; f < FF; ++f) s += V_r[f*HH + h]; v = s; }
    else if (n < 1536) { int h = n-1024; float s = bh[h];  for (int f = 0; f < FF; ++f) s += Vh[f*HH + h];  v = s; }
    else               { v = bgh[n-1536]; }
    bias[n] = v;
    return;
  }
  idx -= 2048;
  if (idx < 65536) {                        // UzrN words (i4, permuted, +8)
    int c  = idx & 1;
    int l  = (idx >> 1) & 63;
    int i  = (idx >> 7) & 3;
    int wv = (idx >> 9) & 7;
    int u  = idx >> 12;                    // 0..15
    int kt = u >> 1, half = u & 1;
    int col = (wv*4 + i)*16 + (l & 15);
    const float* src = half ? U_r : U_z;
    float sc = 7.f / uscale[half*512 + col];
    unsigned int word = 0;
#pragma unroll
    for (int p = 0; p < 8; ++p) {
      int j = c*8 + (p & 1)*4 + (p >> 1);
      int k = kt*64 + (l >> 4)*16 + j;
      float q = fminf(fmaxf(rintf(src[k*HH + col] * sc), -7.f), 7.f);
      unsigned int uq = (unsigned int)((int)q + 8);
      word |= (uq & 0xF) << (4*p);
    }
    UzrN[idx] = word;
    return;
  }
  idx -= 65536;
  if (idx < 32768) {                        // UhN words (i4, permuted, +8)
    int c  = idx & 1;
    int l  = (idx >> 1) & 63;
    int i  = (idx >> 7) & 3;
    int wv = (idx >> 9) & 7;
    int u  = idx >> 12;                    // 0..7 (kt)
    int col = (wv*4 + i)*16 + (l & 15);
    float sc = 7.f / uscale[1024 + col];
    unsigned int word = 0;
#pragma unroll
    for (int p = 0; p < 8; ++p) {
      int j = c*8 + (p & 1)*4 + (p >> 1);
      int k = u*64 + (l >> 4)*16 + j;
      float q = fminf(fmaxf(rintf(Uh[k*HH + col] * sc), -7.f), 7.f);
      unsigned int uq = (unsigned int)((int)q + 8);
      word |= (uq & 0xF) << (4*p);
    }
    UhN[idx] = word;
  }
}

// ---------------------------------------------------------------------------
// K1: imputation + fused A chunk [B*TC][256] bf16 = [x_imp | m]
// ---------------------------------------------------------------------------
__global__ __launch_bounds__(256) void build_A_kernel(
    const float* __restrict__ x, const float* __restrict__ delta,
    const float* __restrict__ mm, const float* __restrict__ xf,
    const float* __restrict__ Wgx, const float* __restrict__ bgx,
    const int* __restrict__ bs, unsigned short* __restrict__ A,
    int t0, int TC)
{
  int blk = blockIdx.x;
  int row8 = blk * 8;
  int b0  = row8 / TC;
  int tl0 = row8 % TC;
  if (b0 >= bs[t0 + tl0]) return;
  int tid = threadIdx.x;
  int rl = row8 + (tid >> 5);
  int tc = tl0 + (tid >> 5);
  long gi = ((long)b0*TT + t0 + tc) * 32 + (tid & 31);
  int f0 = (tid & 31) * 4;
  fvec4 xv = ((const fvec4*)x)[gi];
  fvec4 dv = ((const fvec4*)delta)[gi];
  fvec4 mv = ((const fvec4*)mm)[gi];
  fvec4 fv = ((const fvec4*)xf)[gi];
  unsigned short ox[4], om[4];
#pragma unroll
  for (int j = 0; j < 4; ++j) {
    float g  = __expf(-fmaxf(dv[j]*Wgx[f0+j] + bgx[f0+j], 0.f));
    float xr = g*fv[j] + (1.f - g)*0.001f;
    float xi = (mv[j] > 0.5f) ? xr : xv[j];
    ox[j] = f2bf(xi); om[j] = f2bf(mv[j]);
  }
  *(u16x4*)(A + (long)rl*KK + f0)       = (u16x4){ox[0], ox[1], ox[2], ox[3]};
  *(u16x4*)(A + (long)rl*KK + 128 + f0) = (u16x4){om[0], om[1], om[2], om[3]};
}

// ---------------------------------------------------------------------------
// K2: chunk GEMM  PRE[m][n] = A[m][:] @ Bw[:,n] + bias[n]  (bf16 MFMA, K=256)
// ---------------------------------------------------------------------------
__global__ __launch_bounds__(256) void gemm1_kernel(
    const unsigned short* __restrict__ A, const unsigned short* __restrict__ BwT,
    const float* __restrict__ bias, const int* __restrict__ bs,
    unsigned short* __restrict__ PRE, int t0, int TC)
{
  int blk = blockIdx.x;
  int nt = blk & 15;
  int mt = blk >> 4;
  {
    int m0 = mt * 128;
    int b_ = m0 / TC;
    int bcheck = (TC >= 128) ? bs[t0 + (m0 % TC)] : bs[t0];
    if (b_ >= bcheck) return;
  }
  int tid = threadIdx.x;
  int w = tid >> 6, l = tid & 63;
  int wm = w >> 1, wn = w & 1;
  int lr = l & 15, lg = l >> 4;
  int m_base = mt*128 + wm*64;
  int n_base = nt*128 + wn*64;
  const unsigned short* Aptr = A   + (long)(m_base + lr)*KK + lg*8;
  const unsigned short* Bptr = BwT + (long)(n_base + lr)*KK + lg*8;
  f32x4 acc[4][4];
#pragma unroll
  for (int i = 0; i < 4; ++i)
#pragma unroll
    for (int j = 0; j < 4; ++j) acc[i][j] = (f32x4){0.f, 0.f, 0.f, 0.f};

#pragma unroll
  for (int kt = 0; kt < 8; ++kt) {
    bf16x8 af[4], bfr[4];
#pragma unroll
    for (int i = 0; i < 4; ++i) af[i]  = *(const bf16x8*)(Aptr + (long)i*16*KK + kt*32);
#pragma unroll
    for (int i = 0; i < 4; ++i) bfr[i] = *(const bf16x8*)(Bptr + (long)i*16*KK + kt*32);
#pragma unroll
    for (int ms = 0; ms < 4; ++ms)
#pragma unroll
      for (int ns = 0; ns < 4; ++ns)
        acc[ms][ns] = __builtin_amdgcn_mfma_f32_16x16x32_bf16(af[ms], bfr[ns], acc[ms][ns], 0, 0, 0);
  }
#pragma unroll
  for (int ms = 0; ms < 4; ++ms) {
    int gm0 = m_base + ms*16 + lg*4;
#pragma unroll
    for (int ns = 0; ns < 4; ++ns) {
      int gn = n_base + ns*16 + lr;
      float bv = bias[gn];
      bool is_gamma = (gn >= 1536);
#pragma unroll
      for (int q = 0; q < 4; ++q) {
        float v = acc[ms][ns][q] + bv;
        if (is_gamma) v = __expf(-fmaxf(v, 0.f));
        PRE[(long)(gm0 + q)*NN + gn] = f2bf(v);
      }
    }
  }
}

// ---------------------------------------------------------------------------
// K3: sequential scan, 16 blocks x 512 threads (8 waves), i8 MFMA (K=64).
//   ALL U in int4 nibbles (+8 offset): z/r streamed via depth-4 register
//   prefetch (VGPR loads); Uh via depth-4 glds pipeline (4 x 2KB slots) with
//   counted vmcnt. Offset corrected exactly via rowsum(hd_q)/rowsum(a2_q).
//   Stream: 256(zr) + 128(Uh) + 64(HG) + 32(pzr) = 480 KB/step.
// ---------------------------------------------------------------------------
__global__ __launch_bounds__(512, 2) void scan_kernel(
    const unsigned short* __restrict__ PRE,
    const unsigned int* __restrict__ UzrN,
    const unsigned int* __restrict__ UhN,
    const float* __restrict__ uscale,
    const int* __restrict__ bs,
    float* __restrict__ h_st,
    float* __restrict__ sbuf,
    int t0, int TC)
{
  __shared__ __align__(16) char Ubuf[8][4][2048];          // 64 KB (4-slot Uh dbuf)
  __shared__ __align__(16) i32x4 hd_l[8*64];               // 8 KB hd / a2 frags
  __shared__ __align__(16) unsigned short slabHG[16*1024]; // 32 KB [row][htld|r : gamma]
  __shared__ float hm[16][524];                            // 33.5 KB h master
  __shared__ int hsumW[8][16];                             // hd rowsum partials
  __shared__ int hsumW2[8][16];                            // a2 rowsum partials
  __shared__ float wmax[8];

  const int tid = threadIdx.x;
  const int r0 = blockIdx.x * 16;
  if (t0 > 0 && bs[t0] <= r0) return;

  const int w = tid >> 6, l = tid & 63, lr = l & 15, lg = l >> 4;
  const size_t rowStr = (size_t)TC * NN;

  auto STAGEB = [&](int u) {   // Uh unit u (2 KB): 2 glds of 16B/lane
    const char* src = (const char*)UhN + ((size_t)(u*8 + w))*2048 + (size_t)l*16;
    char* dst = &Ubuf[w][u & 3][0];
    gload16(src, dst);
    gload16(src + 1024, dst + 1024);
  };
  auto STAGEHG = [&](const unsigned short* PREn) {  // htilde+gamma halves, swizzled source
#pragma unroll
    for (int j = 0; j < 4; ++j) {
      int idx = w*4 + j;
      int row = idx >> 1;
      int phys = (idx & 1)*512 + l*8;
      int logi = phys ^ ((row & 7) << 3);
      const unsigned short* src = PREn + (size_t)row*rowStr + 1024 + logi;
      gload16(src, &slabHG[idx*512]);
    }
  };
  auto LOADZR = [&](int u, u32x2* d) {   // z/r unit u: 4 tiles x 8B per thread
#pragma unroll
    for (int i = 0; i < 4; ++i)
      d[i] = ((const u32x2*)UzrN)[((u*8 + w)*4 + i)*64 + l];
  };

  // per-thread dequant constants
  float zdq[4], rdq[4], hdq[4];
#pragma unroll
  for (int i = 0; i < 4; ++i) {
    int c = (w*4 + i)*16 + lr;
    zdq[i] = uscale[c]        * (1.f/889.f);    // 7 * 127
    rdq[i] = uscale[512 + c]  * (1.f/889.f);
    hdq[i] = uscale[1024 + c] * (1.f/889.f);    // 7 * 127 (Uh now i4)
  }
  if (tid < 8) wmax[tid] = (t0 == 0) ? 1e-20f : sbuf[blockIdx.x];

  if (t0 == 0) {
    for (int i = tid; i < 16*512; i += 512) hm[i>>9][i&511] = 0.f;
  } else {
    for (int i = tid; i < 16*512; i += 512)
      hm[i>>9][i&511] = h_st[(size_t)(r0 + (i>>9))*HH + (i&511)];
  }
  asm volatile("s_waitcnt vmcnt(0)" ::: "memory");  // hm loads fully done
  __builtin_amdgcn_sched_barrier(0);

  // prologue staging: HG(step 0), B0, B1  (8 loads outstanding)
  STAGEHG(PRE + (size_t)r0*TC*NN);
  STAGEB(0); STAGEB(1);

  for (int tc = 0; tc < TC; ++tc) {
    const int bsv = bs[t0 + tc];
    if (bsv <= r0) break;                  // descending bs: done forever
    const int na = min(16, bsv - r0);
    const unsigned short* PREstep = PRE + ((size_t)r0*TC + tc)*NN;
    const unsigned short* PREnext = PREstep + NN;

    barrier_lds();                         // S1: prev hm + wmax writes visible
    asm volatile("s_waitcnt vmcnt(4)" ::: "memory");  // HG landed; B0,B1 fly
    __builtin_amdgcn_sched_barrier(0);

    // dynamic quant scale for hd (exact bound: |hd| <= max|h| = s)
    float s = wmax[0];
#pragma unroll
    for (int i = 1; i < 8; ++i) s = fmaxf(s, wmax[i]);
    const float qs = 127.f / s;

    // pz/pr clump (VGPR loads, consumed in epilogue A)
    unsigned short pzr[2][4][4];
#pragma unroll
    for (int i = 0; i < 4; ++i)
#pragma unroll
      for (int q = 0; q < 4; ++q) {
        int row = lg*4 + q, col = (w*4 + i)*16 + lr;
        const unsigned short* pb = PREstep + (size_t)row*rowStr + col;
        pzr[0][i][q] = pb[0];
        pzr[1][i][q] = pb[512];
      }

    // prefetch z/r units 0..3 into registers (depth-4)
    u32x2 inW[4][4];
    LOADZR(0, inW[0]); LOADZR(1, inW[1]);
    LOADZR(2, inW[2]); LOADZR(3, inW[3]);

    // hd build (kt = w): quantize (act? gamma*h : h) to i8 frags + rowsum
    i32x4 qwReg;
    {
      const int k0 = w*64 + lg*16;
      const bool act = lr < na;
      bf16x8 g0 = *(const bf16x8*)&slabHG[hgIdx(lr, 512 + k0)];
      bf16x8 g1 = *(const bf16x8*)&slabHG[hgIdx(lr, 512 + k0 + 8)];
      int psum = 0;
#pragma unroll
      for (int d = 0; d < 4; ++d) {
        int word = 0;
#pragma unroll
        for (int b = 0; b < 4; ++b) {
          int j = d*4 + b;
          float h  = hm[lr][k0 + j];
          float gv = bf2f((unsigned short)(j < 8 ? g0[j] : g1[j-8]));
          float hd = act ? gv*h : h;
          float q  = fminf(fmaxf(rintf(hd*qs), -127.f), 127.f);
          int qi = (int)q;
          psum += qi;
          word |= (qi & 0xFF) << (8*b);
        }
        qwReg[d] = word;
      }
      hd_l[w*64 + l] = qwReg;
      psum += __shfl_xor(psum, 16);
      psum += __shfl_xor(psum, 32);
      if (lg == 0) hsumW[w][lr] = psum;    // wave w's k-range [64w, 64w+64)
    }

    // hoist htilde-preact + gamma for my output cells (before r overwrites)
    float phv[4][4], ggv[4][4];
#pragma unroll
    for (int i = 0; i < 4; ++i)
#pragma unroll
      for (int q = 0; q < 4; ++q) {
        int row = lg*4 + q, col = (w*4 + i)*16 + lr;
        phv[i][q] = bf2f(slabHG[hgIdx(row, col)]);
        ggv[i][q] = bf2f(slabHG[hgIdx(row, 512 + col)]);
      }
    barrier_lds();                         // S2: hd_l + hsumW ready

    // ---- phase A: z|r, 16 units, depth-4 register-streamed i4 ----
    i32x4 acc[8];
#pragma unroll
    for (int i = 0; i < 8; ++i) acc[i] = (i32x4){0, 0, 0, 0};
    i32x4 af;
#pragma unroll
    for (int u = 0; u < 16; ++u) {
      if (!(u & 1)) af = hd_l[(u>>1)*64 + l];
      u32x2* inw = inW[u & 3];
      __builtin_amdgcn_s_setprio(1);
#pragma unroll
      for (int i = 0; i < 4; ++i) {
        unsigned int W0 = inw[i][0], W1 = inw[i][1];
        i32x4 bfr;
        bfr[0] = (int)(W0 & 0x0F0F0F0Fu);
        bfr[1] = (int)((W0 >> 4) & 0x0F0F0F0Fu);
        bfr[2] = (int)(W1 & 0x0F0F0F0Fu);
        bfr[3] = (int)((W1 >> 4) & 0x0F0F0F0Fu);
        acc[(u&1)*4 + i] = __builtin_amdgcn_mfma_i32_16x16x64_i8(af, bfr, acc[(u&1)*4 + i], 0, 0, 0);
      }
      __builtin_amdgcn_s_setprio(0);
      if (u < 12) LOADZR(u + 4, inW[u & 3]);
    }
    // stage Uh units 2,3 now (covered by epilogue A + a2 build)
    STAGEB(2); STAGEB(3);

    // epilogue A: offset-correct, z -> regs; r -> slabHG (cols 0..511)
    int rsum[4];
#pragma unroll
    for (int q = 0; q < 4; ++q) {
      int row = lg*4 + q, t = 0;
#pragma unroll
      for (int w2 = 0; w2 < 8; ++w2) t += hsumW[w2][row];
      rsum[q] = t * 8;
    }
    float zreg[4][4];
#pragma unroll
    for (int i = 0; i < 4; ++i)
#pragma unroll
      for (int q = 0; q < 4; ++q) {
        int row = lg*4 + q, col = (w*4 + i)*16 + lr;
        float az = bf2f(pzr[0][i][q]) + (float)(acc[i][q]   - rsum[q]) * zdq[i] * s;
        float ar = bf2f(pzr[1][i][q]) + (float)(acc[4+i][q] - rsum[q]) * rdq[i] * s;
        zreg[i][q] = 1.f/(1.f + __expf(-az));
        slabHG[hgIdx(row, col)] = f2bf(1.f/(1.f + __expf(-ar)));
      }
    barrier_lds();                         // S3: r ready; phase-A hd_l reads done

    // a2 = hd*r quantized (register hd; same slot rewrite) + a2 rowsum
    {
      const int k0 = w*64 + lg*16;
      bf16x8 r0v = *(const bf16x8*)&slabHG[hgIdx(lr, k0)];
      bf16x8 r1v = *(const bf16x8*)&slabHG[hgIdx(lr, k0 + 8)];
      i32x4 nw;
      int psum2 = 0;
#pragma unroll
      for (int d = 0; d < 4; ++d) {
        int word = qwReg[d], out = 0;
#pragma unroll
        for (int b = 0; b < 4; ++b) {
          int j = d*4 + b;
          int hq = (int)(signed char)((word >> (8*b)) & 0xFF);
          float rv = bf2f((unsigned short)(j < 8 ? r0v[j] : r1v[j-8]));
          float q = fminf(fmaxf(rintf((float)hq * rv), -127.f), 127.f);
          int qi = (int)q;
          psum2 += qi;
          out |= (qi & 0xFF) << (8*b);
        }
        nw[d] = out;
      }
      hd_l[w*64 + l] = nw;
      psum2 += __shfl_xor(psum2, 16);
      psum2 += __shfl_xor(psum2, 32);
      if (lg == 0) hsumW2[w][lr] = psum2;
    }
    barrier_lds();                         // S4: a2 frags + hsumW2 ready

    // ---- phase B: htilde, 8 units, depth-4 glds i4 ----
    // FIFO worst case at entry: [B0,B1,B2,B3] = 8 loads.
    i32x4 accB[4];
#pragma unroll
    for (int i = 0; i < 4; ++i) accB[i] = (i32x4){0, 0, 0, 0};
#pragma unroll
    for (int u = 0; u < 8; ++u) {
      if (u < 5) { asm volatile("s_waitcnt vmcnt(6)" ::: "memory"); }
      else       { asm volatile("s_waitcnt vmcnt(8)" ::: "memory"); }
      __builtin_amdgcn_sched_barrier(0);
      const char* buf = &Ubuf[w][u & 3][0];
      i32x4 af2 = hd_l[u*64 + l];
      __builtin_amdgcn_s_setprio(1);
#pragma unroll
      for (int i = 0; i < 4; ++i) {
        u32x2 Wv = *(const u32x2*)&buf[(i*64 + l)*8];
        unsigned int W0 = Wv[0], W1 = Wv[1];
        i32x4 bfr;
        bfr[0] = (int)(W0 & 0x0F0F0F0Fu);
        bfr[1] = (int)((W0 >> 4) & 0x0F0F0F0Fu);
        bfr[2] = (int)(W1 & 0x0F0F0F0Fu);
        bfr[3] = (int)((W1 >> 4) & 0x0F0F0F0Fu);
        accB[i] = __builtin_amdgcn_mfma_i32_16x16x64_i8(af2, bfr, accB[i], 0, 0, 0);
      }
      __builtin_amdgcn_s_setprio(0);
      __builtin_amdgcn_sched_barrier(0);
      if (u < 4)       STAGEB(u + 4);      // B4..B7 -> slots 0..3 (just freed)
      else if (u == 4) STAGEHG(PREnext);
      else if (u == 5) STAGEB(0);          // next step's B0
      else if (u == 6) STAGEB(1);          // next step's B1
    }

    // epilogue B: h update + block max|h| for next step's quant scale
    int rsum2[4];
#pragma unroll
    for (int q = 0; q < 4; ++q) {
      int row = lg*4 + q, t = 0;
#pragma unroll
      for (int w2 = 0; w2 < 8; ++w2) t += hsumW2[w2][row];
      rsum2[q] = t * 8;
    }
    float mloc = 0.f;
#pragma unroll
    for (int i = 0; i < 4; ++i)
#pragma unroll
      for (int q = 0; q < 4; ++q) {
        int row = lg*4 + q, col = (w*4 + i)*16 + lr;
        float hval;
        if (row < na) {
          float ah = phv[i][q] + (float)(accB[i][q] - rsum2[q]) * hdq[i] * s;
          float e  = __expf(2.f*ah);
          float th = 1.f - 2.f/(e + 1.f);          // tanh, overflow-safe
          float hd = ggv[i][q] * hm[row][col];
          hval = hd + zreg[i][q]*(th - hd);
          hm[row][col] = hval;
        } else {
          hval = hm[row][col];
        }
        mloc = fmaxf(mloc, fabsf(hval));
      }
#pragma unroll
    for (int off = 32; off > 0; off >>= 1) mloc = fmaxf(mloc, __shfl_xor(mloc, off));
    if (l == 0) wmax[w] = fmaxf(mloc, 1e-20f);
  }

  asm volatile("s_waitcnt vmcnt(0)" ::: "memory");  // drain stray prefetches
  barrier_lds();
  for (int i = tid; i < 16*512; i += 512)
    h_st[(size_t)(r0 + (i>>9))*HH + (i&511)] = hm[i>>9][i&511];
  if (tid == 0) {
    float s = wmax[0];
#pragma unroll
    for (int i = 1; i < 8; ++i) s = fmaxf(s, wmax[i]);
    sbuf[blockIdx.x] = s;
  }
}

// ---------------------------------------------------------------------------
// K4: head: eval BatchNorm + decoder GEMV + log_softmax.
//   d_out = [output (256x64) | h_bn (256x512)] fp32
// ---------------------------------------------------------------------------
__global__ __launch_bounds__(64) void head_kernel(
    const float* __restrict__ h_state, const float* __restrict__ decW,
    const float* __restrict__ decb, const float* __restrict__ bnw,
    const float* __restrict__ bnb, float* __restrict__ out)
{
  int b = blockIdx.x, o = threadIdx.x;
  __shared__ float hbn[HH];
  const float s = rsqrtf(1.f + 1e-5f);
  for (int j = o; j < HH; j += 64)
    hbn[j] = h_state[(long)b*HH + j] * (bnw[j] * s) + bnb[j];
  __syncthreads();
  float acc = decb[o];
  for (int j = 0; j < HH; ++j) acc += hbn[j] * decW[j*OO + o];
  float mx = acc;
#pragma unroll
  for (int off = 32; off > 0; off >>= 1) mx = fmaxf(mx, __shfl_xor(mx, off));
  float ex = __expf(acc - mx);
  float sum = ex;
#pragma unroll
  for (int off = 32; off > 0; off >>= 1) sum += __shfl_xor(sum, off);
  out[(long)b*OO + o] = acc - mx - __logf(sum);
  for (int j = o; j < HH; j += 64)
    out[(long)BB*OO + (long)b*HH + j] = hbn[j];
}

// ---------------------------------------------------------------------------
extern "C" void kernel_launch(void* const* d_in, const int* in_sizes, int n_in,
                              void* d_out, int out_size, void* d_ws, size_t ws_size,
                              hipStream_t stream) {
  const float* x     = (const float*)d_in[0];
  const float* delta = (const float*)d_in[1];
  const float* mm    = (const float*)d_in[2];
  const float* xf    = (const float*)d_in[3];
  const int*   bs    = (const int*)  d_in[4];
  const float* W_r   = (const float*)d_in[5];
  const float* U_r   = (const float*)d_in[6];
  const float* V_r   = (const float*)d_in[7];
  const float* b_r   = (const float*)d_in[8];
  const float* W_z   = (const float*)d_in[9];
  const float* U_z   = (const float*)d_in[10];
  const float* V_z   = (const float*)d_in[11];
  const float* b_z   = (const float*)d_in[12];
  const float* W     = (const float*)d_in[13];
  const float* U     = (const float*)d_in[14];
  const float* V     = (const float*)d_in[15];
  const float* b     = (const float*)d_in[16];
  const float* Wgx   = (const float*)d_in[17];
  const float* bgx   = (const float*)d_in[18];
  const float* Wgh   = (const float*)d_in[19];
  const float* bgh   = (const float*)d_in[20];
  const float* decW  = (const float*)d_in[21];
  const float* decb  = (const float*)d_in[22];
  const float* bnw   = (const float*)d_in[23];
  const float* bnb   = (const float*)d_in[24];

  auto rnd = [](size_t v) { return (v + 255) & ~(size_t)255; };
  const size_t fixed_bytes = rnd((size_t)2048*256*2) + rnd(2048*4)
                           + rnd((size_t)256*1024) + rnd((size_t)128*1024)
                           + rnd(1536*4) + rnd(64)
                           + rnd((size_t)BB*HH*4);
  int TC = 0;
  const int cands[5] = {128, 64, 32, 16, 8};
  for (int i = 0; i < 5; ++i) {
    size_t need = fixed_bytes + rnd((size_t)BB*cands[i]*KK*2) + rnd((size_t)BB*cands[i]*NN*2);
    if (need <= ws_size) { TC = cands[i]; break; }
  }
  if (TC == 0) return;

  char* p = (char*)d_ws;
  auto alloc = [&](size_t bytes) { char* r = p; p += (bytes + 255) & ~(size_t)255; return r; };
  unsigned short* A_chunk = (unsigned short*)alloc((size_t)BB * TC * KK * 2);
  unsigned short* PREc    = (unsigned short*)alloc((size_t)BB * TC * NN * 2);
  unsigned short* BwT     = (unsigned short*)alloc((size_t)2048 * 256 * 2);
  float*          bias    = (float*)alloc(2048 * 4);
  unsigned int*   UzrN    = (unsigned int*)alloc((size_t)256 * 1024);
  unsigned int*   UhN     = (unsigned int*)alloc((size_t)128 * 1024);
  float*          uscale  = (float*)alloc(1536 * 4);
  float*          sbuf    = (float*)alloc(64);
  float*          h_st    = (float*)alloc((size_t)BB * HH * 4);

  prep_scales_kernel<<<6, 256, 0, stream>>>(U_z, U_r, U, uscale);
  prep_kernel<<<2440, 256, 0, stream>>>(W_z, V_z, b_z, W_r, V_r, b_r, W, V, b,
                                        Wgh, bgh, U_z, U_r, U, uscale,
                                        BwT, bias, UzrN, UhN);
  const int nch = TT / TC;
  for (int c = 0; c < nch; ++c) {
    int t0 = c * TC;
    build_A_kernel<<<BB*TC/8, 256, 0, stream>>>(x, delta, mm, xf, Wgx, bgx, bs,
                                                A_chunk, t0, TC);
    gemm1_kernel<<<(BB*TC/128)*16, 256, 0, stream>>>(A_chunk, BwT, bias, bs,
                                                     PREc, t0, TC);
    scan_kernel<<<16, 512, 0, stream>>>(PREc, UzrN, UhN, uscale, bs,
                                        h_st, sbuf, t0, TC);
  }
  head_kernel<<<256, 64, 0, stream>>>(h_st, decW, decb, bnw, bnb, (float*)d_out);
}